// Round 1
// baseline (2995.998 us; speedup 1.0000x reference)
//
#include <hip/hip_runtime.h>
#include <stdint.h>

#define HDIM  4096
#define VOCAB 32000
#define BT    4096
#define IGN   (-100)

typedef __attribute__((ext_vector_type(8))) short short8;
typedef __attribute__((ext_vector_type(4))) float f32x4;

// ---------------- f32 -> bf16 (RNE), header-free ----------------
__device__ __forceinline__ unsigned short f2bf(float x) {
  unsigned int u = __builtin_bit_cast(unsigned int, x);
  u += 0x7fffu + ((u >> 16) & 1u);
  return (unsigned short)(u >> 16);
}

__global__ void cvt_kernel(const float* __restrict__ in, unsigned short* __restrict__ out, int n4) {
  int idx = blockIdx.x * blockDim.x + threadIdx.x;
  int stride = gridDim.x * blockDim.x;
  const float4* in4 = (const float4*)in;
  ushort4* out4 = (ushort4*)out;
  for (int i = idx; i < n4; i += stride) {
    float4 v = in4[i];
    ushort4 o;
    o.x = f2bf(v.x); o.y = f2bf(v.y); o.z = f2bf(v.z); o.w = f2bf(v.w);
    out4[i] = o;
  }
}

// ---------------- target logits, full f32 precision ----------------
__global__ __launch_bounds__(256) void tgt_kernel(
    const float* __restrict__ x_p, const float* __restrict__ w_p, const float* __restrict__ b_p,
    const float* __restrict__ x_r, const float* __restrict__ w_r, const float* __restrict__ b_r,
    const int* __restrict__ target, float* __restrict__ out /* [2][BT] */) {
  const int model = blockIdx.y;
  const float* x = model ? x_r : x_p;
  const float* w = model ? w_r : w_p;
  const float* b = model ? b_r : b_p;
  const int wave = threadIdx.x >> 6, lane = threadIdx.x & 63;
  const int token = blockIdx.x * 4 + wave;
  int y = target[token];
  int ys = (y < 0) ? 0 : y;
  const float4* xr = (const float4*)(x + (size_t)token * HDIM);
  const float4* wr = (const float4*)(w + (size_t)ys * HDIM);
  float acc = 0.f;
#pragma unroll
  for (int it = 0; it < 16; ++it) {
    float4 a = xr[lane + 64 * it];
    float4 bv = wr[lane + 64 * it];
    acc += a.x * bv.x + a.y * bv.y + a.z * bv.z + a.w * bv.w;
  }
#pragma unroll
  for (int m = 32; m >= 1; m >>= 1) acc += __shfl_xor(acc, m, 64);
  if (lane == 0) out[model * BT + token] = acc + b[ys];
}

// ---------------- fused GEMM + sum-exp epilogue ----------------
// 256x256 tile, BK=64, 512 threads = 8 waves (2M x 4N), 128x64 per wave.
// Counted-vmcnt software pipeline (T3/T4): LO/HI half-regions retire per
// phase; next tiles' halves are staged into retired regions. vmcnt(4) once
// per K-tile, 2 barriers per K-tile, never a vmcnt(0) drain in the loop.
typedef __attribute__((address_space(1))) void gvoid_t;
typedef __attribute__((address_space(3))) void lvoid_t;
__device__ __forceinline__ void load_lds16(const void* g, void* l) {
  __builtin_amdgcn_global_load_lds((gvoid_t*)g, (lvoid_t*)l, 16, 0, 0);
}

__global__ __launch_bounds__(512, 2) void gemm_lse_kernel(
    const unsigned short* __restrict__ Xp, const unsigned short* __restrict__ Wp, const float* __restrict__ bp,
    const unsigned short* __restrict__ Xr, const unsigned short* __restrict__ Wr, const float* __restrict__ br,
    float* __restrict__ rowsum /* [2][BT] */) {
  const int model = blockIdx.y;
  const unsigned short* X = model ? Xr : Xp;
  const unsigned short* W = model ? Wr : Wp;
  const float* bias = model ? br : bp;
  float* rs = rowsum + model * BT;

  // 2 double-buffered 256x64 bf16 tiles: 2*32KB (A) + 2*32KB (B) = 128 KB
  __shared__ __align__(16) unsigned short As[2 * 256 * 64];
  __shared__ __align__(16) unsigned short Bs[2 * 256 * 64];
  __shared__ float redbuf[4][256];  // 4 KB epilogue cross-wave reduce

  const int tid = threadIdx.x;
  const int mtile = blockIdx.x & 15;   // mtile-fast: 16 row-tiles share one W col-tile in L2/LLC
  const int ntile = blockIdx.x >> 4;
  const int row0 = mtile * 256;
  const int col0 = ntile * 256;
  const int lane = tid & 63;
  const int wave = tid >> 6;
  const int wr = wave >> 2, wc = wave & 3;   // wave sub-tile: rows wr*128, cols wc*64
  const int q = lane >> 4, c = lane & 15;

  // ---- staging map: group g = 8 rows; thread loads 16B chunk (row g*8+lr, col lc*8^swz)
  // LDS dest = linear (base + lane*16B) as required by global_load_lds; swizzle on global src.
  const int lr = lane >> 3, lc = lane & 7;
  const int swz8 = ((lc ^ lr) << 3);            // element col within 64, pre-swizzled
  const int bgrp = ((wave >> 2) << 3) + (wave & 3);
  const unsigned short* Xb = X + (size_t)row0 * HDIM;
  const unsigned short* Wb = W + (size_t)col0 * HDIM;
  // region groups: A-LO = {wave, wave+16} (rows 0-63,128-191); A-HI = {wave+8, wave+24}
  //                B-LO = {bgrp, bgrp+16} (rows 0-31,64-95,128-159,192-223); B-HI = {bgrp+4, bgrp+20}

  // ---- fragment read map (XOR-deswizzle on read side)
  const int ksw = (c & 7) << 3;
  const int k0 = (q * 8) ^ ksw;
  const int k1 = k0 ^ 32;
  const int aBase = (wr * 128 + c) * 64;
  const int bBase = (wc * 64 + c) * 64;

  f32x4 acc[8][4] = {};
  short8 a0[4][2], b0[2][2], b1[2][2];

#define ST_A(bb, g, kk) load_lds16(Xb + (size_t)(((g) << 3) + lr) * HDIM + (kk) + swz8, &As[((bb) << 14) + ((g) << 9) + (lane << 3)])
#define ST_B(bb, g, kk) load_lds16(Wb + (size_t)(((g) << 3) + lr) * HDIM + (kk) + swz8, &Bs[((bb) << 14) + ((g) << 9) + (lane << 3)])
#define DS_A(bo, i, kk) (*(const short8*)&As[(bo) + aBase + ((i) << 10) + (kk)])
#define DS_B(bo, j, kk) (*(const short8*)&Bs[(bo) + bBase + ((j) << 10) + (kk)])
#define READS_A(bo, ib) do { \
    a0[0][0] = DS_A(bo, (ib) + 0, k0); a0[0][1] = DS_A(bo, (ib) + 0, k1); \
    a0[1][0] = DS_A(bo, (ib) + 1, k0); a0[1][1] = DS_A(bo, (ib) + 1, k1); \
    a0[2][0] = DS_A(bo, (ib) + 2, k0); a0[2][1] = DS_A(bo, (ib) + 2, k1); \
    a0[3][0] = DS_A(bo, (ib) + 3, k0); a0[3][1] = DS_A(bo, (ib) + 3, k1); \
  } while (0)
#define READS_B(bo, jb, arr) do { \
    arr[0][0] = DS_B(bo, (jb) + 0, k0); arr[0][1] = DS_B(bo, (jb) + 0, k1); \
    arr[1][0] = DS_B(bo, (jb) + 1, k0); arr[1][1] = DS_B(bo, (jb) + 1, k1); \
  } while (0)
#define MFMA_Q(I0, J0, BB) do { \
    _Pragma("unroll") for (int i_ = 0; i_ < 4; ++i_) \
    _Pragma("unroll") for (int j_ = 0; j_ < 2; ++j_) { \
      acc[(I0) + i_][(J0) + j_] = __builtin_amdgcn_mfma_f32_16x16x32_bf16(a0[i_][0], BB[j_][0], acc[(I0) + i_][(J0) + j_], 0, 0, 0); \
      acc[(I0) + i_][(J0) + j_] = __builtin_amdgcn_mfma_f32_16x16x32_bf16(a0[i_][1], BB[j_][1], acc[(I0) + i_][(J0) + j_], 0, 0, 0); \
    } \
  } while (0)
// One K-tile window. S0/S1 stage kt+1 HI halves (other buffer, always free);
// S2/S3 stage kt+2 LO halves into regions this window retired at p0 (guarded
// by the mid barrier). WCNT = counted vmcnt before the trailing barrier.
#define WINDOW(bo_, S0, S1, S2, S3, WCNT) do { \
    READS_A(bo_, 0); READS_B(bo_, 0, b0); \
    S0; \
    __builtin_amdgcn_s_setprio(1); MFMA_Q(0, 0, b0); __builtin_amdgcn_s_setprio(0); \
    READS_B(bo_, 2, b1); \
    S1; \
    __builtin_amdgcn_s_setprio(1); MFMA_Q(0, 2, b1); __builtin_amdgcn_s_setprio(0); \
    __builtin_amdgcn_s_barrier(); __builtin_amdgcn_sched_barrier(0); \
    READS_A(bo_, 4); \
    S2; \
    __builtin_amdgcn_s_setprio(1); MFMA_Q(4, 0, b0); __builtin_amdgcn_s_setprio(0); \
    S3; \
    __builtin_amdgcn_s_setprio(1); MFMA_Q(4, 2, b1); __builtin_amdgcn_s_setprio(0); \
    WCNT; \
    __builtin_amdgcn_s_barrier(); __builtin_amdgcn_sched_barrier(0); \
  } while (0)

  // ---- prologue: kt0 fully + kt1 LO halves in flight; wait kt0 (vmcnt(4)) only
  ST_A(0, wave, 0); ST_A(0, wave + 16, 0);
  ST_B(0, bgrp, 0); ST_B(0, bgrp + 16, 0);
  ST_A(0, wave + 8, 0); ST_A(0, wave + 24, 0);
  ST_B(0, bgrp + 4, 0); ST_B(0, bgrp + 20, 0);
  ST_A(1, wave, 64); ST_A(1, wave + 16, 64);
  ST_B(1, bgrp, 64); ST_B(1, bgrp + 16, 64);
  asm volatile("s_waitcnt vmcnt(4)" ::: "memory");
  __builtin_amdgcn_s_barrier();
  __builtin_amdgcn_sched_barrier(0);

  // ---- main loop: 64 K-tiles; steady state keeps 2 half-tiles (4 loads) in flight
  for (int t = 0; t < 62; ++t) {
    const int b = t & 1;
    const int bo_ = b << 14;
    const int kn = (t + 1) << 6;
    const int kn2 = (t + 2) << 6;
    WINDOW(bo_,
           (ST_A(b ^ 1, wave + 8, kn), ST_A(b ^ 1, wave + 24, kn)),
           (ST_B(b ^ 1, bgrp + 4, kn), ST_B(b ^ 1, bgrp + 20, kn)),
           (ST_A(b, wave, kn2), ST_A(b, wave + 16, kn2)),
           (ST_B(b, bgrp, kn2), ST_B(b, bgrp + 16, kn2)),
           asm volatile("s_waitcnt vmcnt(4)" ::: "memory"));
  }
  // t = 62: stage last tile's HI halves, then drain everything once
  WINDOW(0,
         (ST_A(1, wave + 8, 4032), ST_A(1, wave + 24, 4032)),
         (ST_B(1, bgrp + 4, 4032), ST_B(1, bgrp + 20, 4032)),
         (void)0,
         (void)0,
         asm volatile("s_waitcnt vmcnt(0)" ::: "memory"));
  // t = 63: all data resident; no stages, no barriers needed
  {
    const int bo_ = 1 << 14;
    READS_A(bo_, 0); READS_B(bo_, 0, b0);
    MFMA_Q(0, 0, b0);
    READS_B(bo_, 2, b1);
    MFMA_Q(0, 2, b1);
    READS_A(bo_, 4);
    MFMA_Q(4, 0, b0);
    MFMA_Q(4, 2, b1);
  }
#undef WINDOW
#undef MFMA_Q
#undef READS_B
#undef READS_A
#undef DS_B
#undef DS_A
#undef ST_B
#undef ST_A

  // ---- epilogue: per-row sum of exp(logit + bias) over this 256-col tile.
  // C/D layout: row = wr*128 + i*16 + q*4 + reg ; col = wc*64 + j*16 + c
  float bb[4];
#pragma unroll
  for (int j = 0; j < 4; ++j) bb[j] = bias[col0 + wc * 64 + j * 16 + c];

#pragma unroll
  for (int i = 0; i < 8; ++i) {
#pragma unroll
    for (int reg = 0; reg < 4; ++reg) {
      float v = 0.f;
#pragma unroll
      for (int j = 0; j < 4; ++j) v += __expf(acc[i][j][reg] + bb[j]);
      v += __shfl_xor(v, 1, 64);
      v += __shfl_xor(v, 2, 64);
      v += __shfl_xor(v, 4, 64);
      v += __shfl_xor(v, 8, 64);
      if (c == 0) redbuf[wc][wr * 128 + i * 16 + q * 4 + reg] = v;
    }
  }
  __syncthreads();
  if (tid < 256) {
    float tot = redbuf[0][tid] + redbuf[1][tid] + redbuf[2][tid] + redbuf[3][tid];
    atomicAdd(&rs[row0 + tid], tot);
  }
}

// ---------------- per-sequence logp sums (double) ----------------
__global__ __launch_bounds__(512) void seq_kernel(
    const float* __restrict__ tgt, const float* __restrict__ rowsum,
    const int* __restrict__ target, double* __restrict__ seqlp /* [2][8] */) {
  const int model = blockIdx.x >> 3;
  const int seq = blockIdx.x & 7;
  const int token = seq * 512 + threadIdx.x;
  int y = target[token];
  float lp = 0.f;
  if (y != IGN) lp = tgt[model * BT + token] - __logf(rowsum[model * BT + token]);
  __shared__ double sbuf[512];
  sbuf[threadIdx.x] = (double)lp;
  __syncthreads();
  for (int s = 256; s > 0; s >>= 1) {
    if (threadIdx.x < s) sbuf[threadIdx.x] += sbuf[threadIdx.x + s];
    __syncthreads();
  }
  if (threadIdx.x == 0) seqlp[model * 8 + seq] = sbuf[0];
}

// ---------------- final DPO loss ----------------
__global__ void final_kernel(const double* __restrict__ seqlp, float* __restrict__ out) {
  if (threadIdx.x == 0) {
    double loss = 0.0;
    for (int i = 0; i < 4; ++i) {
      double cp = seqlp[i], rp = seqlp[4 + i];
      double rc = seqlp[8 + i], rr = seqlp[12 + i];
      double d = 0.1 * ((cp - rc) - (rp - rr));
      double z = -d;  // -log_sigmoid(d) = softplus(-d)
      loss += fmax(z, 0.0) + log1p(exp(-fabs(z)));
    }
    out[0] = (float)(loss / 4.0);
  }
}

extern "C" void kernel_launch(void* const* d_in, const int* in_sizes, int n_in,
                              void* d_out, int out_size, void* d_ws, size_t ws_size,
                              hipStream_t stream) {
  const float* x_p = (const float*)d_in[0];
  const float* w_p = (const float*)d_in[1];
  const float* b_p = (const float*)d_in[2];
  const float* x_r = (const float*)d_in[3];
  const float* w_r = (const float*)d_in[4];
  const float* b_r = (const float*)d_in[5];
  const int* target = (const int*)d_in[6];

  char* ws = (char*)d_ws;
  size_t off = 0;
  auto take = [&](size_t bytes) {
    char* p = ws + off;
    off = (off + bytes + 255) & ~(size_t)255;
    return p;
  };
  unsigned short* Xp = (unsigned short*)take((size_t)BT * HDIM * 2);
  unsigned short* Xr = (unsigned short*)take((size_t)BT * HDIM * 2);
  unsigned short* Wp = (unsigned short*)take((size_t)VOCAB * HDIM * 2);
  unsigned short* Wr = (unsigned short*)take((size_t)VOCAB * HDIM * 2);
  float* rowsum = (float*)take(2 * BT * sizeof(float));
  float* tgt = (float*)take(2 * BT * sizeof(float));
  double* seqlp = (double*)take(16 * sizeof(double));

  hipMemsetAsync(rowsum, 0, 2 * BT * sizeof(float), stream);

  cvt_kernel<<<4096, 256, 0, stream>>>(x_p, Xp, BT * HDIM / 4);
  cvt_kernel<<<4096, 256, 0, stream>>>(x_r, Xr, BT * HDIM / 4);
  cvt_kernel<<<8192, 256, 0, stream>>>(w_p, Wp, VOCAB * HDIM / 4);
  cvt_kernel<<<8192, 256, 0, stream>>>(w_r, Wr, VOCAB * HDIM / 4);

  tgt_kernel<<<dim3(BT / 4, 2), 256, 0, stream>>>(x_p, w_p, b_p, x_r, w_r, b_r, target, tgt);

  gemm_lse_kernel<<<dim3(16 * (VOCAB / 256), 2), 512, 0, stream>>>(Xp, Wp, b_p, Xr, Wr, b_r, rowsum);

  seq_kernel<<<16, 512, 0, stream>>>(tgt, rowsum, target, seqlp);
  final_kernel<<<1, 64, 0, stream>>>(seqlp, (float*)d_out);
}